// Round 1
// baseline (355.523 us; speedup 1.0000x reference)
//
#include <hip/hip_runtime.h>
#include <hip/hip_bf16.h>
#include <math.h>

// Problem constants
#define BATCH 1024
#define NREAL 784
#define NPAD  896      // 7*128, zero-padded graph dim
#define C1D   32
#define C2D   32
#define HDIM  512
#define NCLS  10
#define KFC   25088    // 784*32
#define KSLICES 8
#define KPERSLICE 3136 // 25088/8

// GEMM tile
#define BM 128
#define BN 128
#define BK 32

using bf16x8  = __attribute__((ext_vector_type(8))) __bf16;
using floatx4 = __attribute__((ext_vector_type(4))) float;

__device__ __forceinline__ void gll16(const void* g, void* l) {
    // async global->LDS, 16B per lane; LDS dest is wave-uniform base + lane*16
    __builtin_amdgcn_global_load_lds((const __attribute__((address_space(1))) void*)g,
                                     (__attribute__((address_space(3))) void*)l,
                                     16, 0, 0);
}

__device__ __forceinline__ float elu_f(float t) {
    return t > 0.f ? t : (__expf(t) - 1.f);
}

// ---------------------------------------------------------------------------
// BT-GEMM: C[row][col] = sum_k A[row][k] * Bm[col][k]   (both k-contiguous)
// 128x128 tile, 256 thr (4 waves, 2x2 of 64x64), BK=32, mfma 16x16x32 bf16.
// MODE 0: plain fp32 store to outF[row*ldc+col]                       (G1)
// MODE 1: elu(acc+bias[col&31]) -> bf16 outH[(col>>5)*KFC+row*32+(col&31)],
//         masked to row<784                                           (G3)
// MODE 2: fp32 partial store outF[z*BATCH*HDIM + row*ldc + col]       (G4)
// ---------------------------------------------------------------------------
template<int MODE>
__launch_bounds__(256)
__global__ void gemm_bt(const __hip_bfloat16* __restrict__ A, int lda,
                        const __hip_bfloat16* __restrict__ Bm, int ldb,
                        int kIters, int kPerZ,
                        float* __restrict__ outF, int ldc,
                        __hip_bfloat16* __restrict__ outH,
                        const float* __restrict__ bias)
{
    __shared__ __align__(16) __hip_bfloat16 As[BM * BK];
    __shared__ __align__(16) __hip_bfloat16 Bs[BN * BK];

    const int tid  = threadIdx.x;
    const int lane = tid & 63;
    const int wave = tid >> 6;
    const int wi = wave >> 1, wj = wave & 1;

    const int m0 = blockIdx.y * BM;
    const int n0 = blockIdx.x * BN;
    const int kBase = blockIdx.z * kPerZ;

    const int rowInChunk = lane >> 2;       // 16 rows per 1KB chunk
    const int kOff8 = (lane & 3) * 8;       // 4 lanes cover 32 bf16 per row

    floatx4 acc[4][4];
    const floatx4 zero4 = {0.f, 0.f, 0.f, 0.f};
    #pragma unroll
    for (int i = 0; i < 4; i++)
        #pragma unroll
        for (int j = 0; j < 4; j++) acc[i][j] = zero4;

    for (int kt = 0; kt < kIters; ++kt) {
        const int k0 = kBase + kt * BK;
        #pragma unroll
        for (int c = 0; c < 2; c++) {
            const int chunk = wave * 2 + c;
            const int r = chunk * 16 + rowInChunk;
            gll16(A  + (size_t)(m0 + r) * lda + k0 + kOff8, As + chunk * 512);
            gll16(Bm + (size_t)(n0 + r) * ldb + k0 + kOff8, Bs + chunk * 512);
        }
        __syncthreads();   // drains vmcnt(0) incl. global_load_lds

        bf16x8 af[4], bfr[4];
        #pragma unroll
        for (int mi = 0; mi < 4; mi++)
            af[mi] = *(const bf16x8*)(As + (wi * 64 + mi * 16 + (lane & 15)) * BK + (lane >> 4) * 8);
        #pragma unroll
        for (int nj = 0; nj < 4; nj++)
            bfr[nj] = *(const bf16x8*)(Bs + (wj * 64 + nj * 16 + (lane & 15)) * BK + (lane >> 4) * 8);

        #pragma unroll
        for (int mi = 0; mi < 4; mi++)
            #pragma unroll
            for (int nj = 0; nj < 4; nj++)
                acc[mi][nj] = __builtin_amdgcn_mfma_f32_16x16x32_bf16(af[mi], bfr[nj], acc[mi][nj], 0, 0, 0);

        __syncthreads();
    }

    // epilogue: C/D layout col=lane&15, row=(lane>>4)*4+reg  [verified m89/m91]
    #pragma unroll
    for (int mi = 0; mi < 4; mi++) {
        #pragma unroll
        for (int nj = 0; nj < 4; nj++) {
            #pragma unroll
            for (int r = 0; r < 4; r++) {
                const int row = m0 + wi * 64 + mi * 16 + (lane >> 4) * 4 + r;
                const int col = n0 + wj * 64 + nj * 16 + (lane & 15);
                const float v = acc[mi][nj][r];
                if (MODE == 0) {
                    outF[(size_t)row * ldc + col] = v;
                } else if (MODE == 1) {
                    if (row < NREAL) {
                        const int c = col & 31, b = col >> 5;
                        const float t = elu_f(v + bias[c]);
                        outH[(size_t)b * KFC + row * 32 + c] = __float2bfloat16(t);
                    }
                } else {
                    outF[(size_t)blockIdx.z * (BATCH * HDIM) + (size_t)row * ldc + col] = v;
                }
            }
        }
    }
}

// ---------------------------------------------------------------------------
// Conversions / padding
// ---------------------------------------------------------------------------
__global__ void convX(const float* __restrict__ x, __hip_bfloat16* __restrict__ Xbf) {
    const int idx = blockIdx.x * 256 + threadIdx.x;
    if (idx >= BATCH * NPAD) return;
    const int m = idx % NPAD, b = idx / NPAD;
    const float v = (m < NREAL) ? x[(size_t)b * NREAL + m] : 0.f;
    Xbf[idx] = __float2bfloat16(v);
}

__global__ void convA(const float* __restrict__ a, __hip_bfloat16* __restrict__ Abf) {
    const int idx = blockIdx.x * 256 + threadIdx.x;
    if (idx >= NPAD * NPAD) return;
    const int m = idx % NPAD, n = idx / NPAD;
    const float v = (m < NREAL && n < NREAL) ? a[(size_t)n * NREAL + m] : 0.f;
    Abf[idx] = __float2bfloat16(v);
}

// wf1 [25088][512] fp32 -> Wt [512][25088] bf16 (LDS tile transpose)
__global__ void convW(const float* __restrict__ wf1, __hip_bfloat16* __restrict__ Wt) {
    __shared__ float tile[32][33];
    const int k0 = blockIdx.x * 32, h0 = blockIdx.y * 32;
    const int tx = threadIdx.x, ty = threadIdx.y;  // (32,8)
    #pragma unroll
    for (int i = 0; i < 4; i++)
        tile[ty * 4 + i][tx] = wf1[(size_t)(k0 + ty * 4 + i) * HDIM + h0 + tx];
    __syncthreads();
    #pragma unroll
    for (int i = 0; i < 4; i++)
        Wt[(size_t)(h0 + ty * 4 + i) * KFC + k0 + tx] = __float2bfloat16(tile[tx][ty * 4 + i]);
}

// ---------------------------------------------------------------------------
// Layer-1 fused pointwise: T_t[(b*32+c)][m] = sum_c' elu(Y[b][m]*w1[c']+b1[c'])*W2[c'][c]
// ---------------------------------------------------------------------------
__global__ void layer1_fuse(const float* __restrict__ Y,
                            const float* __restrict__ w1, const float* __restrict__ b1,
                            const float* __restrict__ w2,
                            __hip_bfloat16* __restrict__ Tt)
{
    __shared__ __align__(16) float sW2[C1D * C2D];
    __shared__ float sw1[C1D], sb1[C1D];
    const int tid = threadIdx.x;                 // 128 threads
    for (int i = tid; i < C1D * C2D; i += 128) sW2[i] = w2[i];
    if (tid < C1D) { sw1[tid] = w1[tid]; sb1[tid] = b1[tid]; }
    __syncthreads();

    const int m = blockIdx.x * 128 + tid;        // 0..895
    const int b = blockIdx.y;
    const float y = Y[(size_t)b * NPAD + m];     // padded cols are exact 0

    float h[C1D];
    #pragma unroll
    for (int c1 = 0; c1 < C1D; c1++) h[c1] = elu_f(y * sw1[c1] + sb1[c1]);

    float4 t4[8];
    #pragma unroll
    for (int q = 0; q < 8; q++) t4[q] = make_float4(0.f, 0.f, 0.f, 0.f);
    #pragma unroll
    for (int c1 = 0; c1 < C1D; c1++) {
        const float hv = h[c1];
        const float4* row = (const float4*)(sW2 + c1 * C2D);
        #pragma unroll
        for (int q = 0; q < 8; q++) {
            const float4 w = row[q];
            t4[q].x += hv * w.x; t4[q].y += hv * w.y;
            t4[q].z += hv * w.z; t4[q].w += hv * w.w;
        }
    }
    const float* tf = (const float*)t4;
    #pragma unroll
    for (int c = 0; c < C2D; c++)
        Tt[((size_t)(b * 32 + c)) * NPAD + m] = __float2bfloat16(tf[c]);
}

// ---------------------------------------------------------------------------
// fc1 split-K reduce: h3[b][h] = relu(bf1[h] + sum_z part[z][b][h])
// ---------------------------------------------------------------------------
__global__ void reduceFc1(const float* __restrict__ part, const float* __restrict__ bf1,
                          float* __restrict__ h3)
{
    const int idx = blockIdx.x * 256 + threadIdx.x;
    if (idx >= BATCH * HDIM) return;
    float s = 0.f;
    #pragma unroll
    for (int z = 0; z < KSLICES; z++) s += part[(size_t)z * BATCH * HDIM + idx];
    s += bf1[idx & (HDIM - 1)];
    h3[idx] = s > 0.f ? s : 0.f;
}

// ---------------------------------------------------------------------------
// fc2 + softmax: one wave per batch row
// ---------------------------------------------------------------------------
__global__ void fc2_softmax(const float* __restrict__ h3, const float* __restrict__ wf2,
                            const float* __restrict__ bf2, float* __restrict__ out)
{
    __shared__ float sW[HDIM * NCLS];
    __shared__ float sb[NCLS];
    const int tid = threadIdx.x;                 // 256
    for (int i = tid; i < HDIM * NCLS; i += 256) sW[i] = wf2[i];
    if (tid < NCLS) sb[tid] = bf2[tid];
    __syncthreads();

    const int lane = tid & 63, wave = tid >> 6;
    const int b = blockIdx.x * 4 + wave;

    float acc[NCLS];
    #pragma unroll
    for (int c = 0; c < NCLS; c++) acc[c] = 0.f;
    #pragma unroll
    for (int q = 0; q < 8; q++) {
        const int h = q * 64 + lane;
        const float hv = h3[(size_t)b * HDIM + h];
        #pragma unroll
        for (int c = 0; c < NCLS; c++) acc[c] += hv * sW[h * NCLS + c];
    }
    #pragma unroll
    for (int c = 0; c < NCLS; c++) {
        #pragma unroll
        for (int off = 32; off >= 1; off >>= 1) acc[c] += __shfl_down(acc[c], off);
    }
    if (lane == 0) {
        float mx = -1e30f;
        #pragma unroll
        for (int c = 0; c < NCLS; c++) { acc[c] += sb[c]; mx = fmaxf(mx, acc[c]); }
        float e[NCLS], s = 0.f;
        #pragma unroll
        for (int c = 0; c < NCLS; c++) { e[c] = __expf(acc[c] - mx); s += e[c]; }
        const float inv = 1.f / s;
        #pragma unroll
        for (int c = 0; c < NCLS; c++) out[(size_t)b * NCLS + c] = e[c] * inv;
    }
}

// ---------------------------------------------------------------------------
// Workspace layout (peak ~119 MB; Wt/part overlay the dead Tt region)
//   off 0         : Abf  [896][896]  bf16   1,605,632
//   off 1605632   : Xbf  [1024][896] bf16   1,835,008
//   off 3440640   : Y    [1024][896] fp32   3,670,016
//   off 7110656   : Tt   [32768][896] bf16 58,720,256   (dead after G3)
//   off 7110656   : Wt   [512][25088] bf16 25,690,112   (overlay, after G3)
//   off 32800768  : part [8][1024][512] f32 16,777,216  (overlay, after G3)
//   off 65830912  : h2f  [1024][25088] bf16 51,380,224
//   off 117211136 : h3   [1024][512] fp32    2,097,152
// ---------------------------------------------------------------------------
extern "C" void kernel_launch(void* const* d_in, const int* in_sizes, int n_in,
                              void* d_out, int out_size, void* d_ws, size_t ws_size,
                              hipStream_t stream)
{
    const float* x   = (const float*)d_in[0];
    const float* a   = (const float*)d_in[1];
    const float* w1  = (const float*)d_in[2];
    const float* b1  = (const float*)d_in[3];
    const float* w2  = (const float*)d_in[4];
    const float* b2  = (const float*)d_in[5];
    const float* wf1 = (const float*)d_in[6];
    const float* bf1 = (const float*)d_in[7];
    const float* wf2 = (const float*)d_in[8];
    const float* bf2 = (const float*)d_in[9];
    float* out = (float*)d_out;

    char* ws = (char*)d_ws;
    __hip_bfloat16* Abf = (__hip_bfloat16*)(ws + 0);
    __hip_bfloat16* Xbf = (__hip_bfloat16*)(ws + 1605632);
    float*          Y   = (float*)(ws + 3440640);
    __hip_bfloat16* Tt  = (__hip_bfloat16*)(ws + 7110656);
    __hip_bfloat16* Wt  = (__hip_bfloat16*)(ws + 7110656);   // overlays Tt (after G3)
    float*          part= (float*)(ws + 32800768);            // overlays Tt (after G3)
    __hip_bfloat16* h2f = (__hip_bfloat16*)(ws + 65830912);
    float*          h3  = (float*)(ws + 117211136);

    convX<<<(BATCH * NPAD + 255) / 256, 256, 0, stream>>>(x, Xbf);
    convA<<<(NPAD * NPAD + 255) / 256, 256, 0, stream>>>(a, Abf);

    // G1: Y[b][n] = sum_m Xbf[b][m] * Abf[n][m]   (M=1024, N=896, K=896)
    gemm_bt<0><<<dim3(NPAD / BN, BATCH / BM, 1), 256, 0, stream>>>(
        Xbf, NPAD, Abf, NPAD, NPAD / BK, 0, Y, NPAD, nullptr, nullptr);

    // layer-1 pointwise + @W2, transposed store
    layer1_fuse<<<dim3(NPAD / 128, BATCH), 128, 0, stream>>>(Y, w1, b1, w2, Tt);

    // G3: h2 = elu(A @ T + b2);  C[n][(b,c)] (M=896, N=32768, K=896)
    gemm_bt<1><<<dim3((BATCH * 32) / BN, NPAD / BM, 1), 256, 0, stream>>>(
        Abf, NPAD, Tt, NPAD, NPAD / BK, 0, nullptr, 0, h2f, b2);

    // transpose wf1 -> bf16 (into the now-dead Tt region)
    convW<<<dim3(KFC / 32, HDIM / 32), dim3(32, 8), 0, stream>>>(wf1, Wt);

    // G4: fc1 partials, split-K=8 (M=1024, N=512, K=3136/slice)
    gemm_bt<2><<<dim3(HDIM / BN, BATCH / BM, KSLICES), 256, 0, stream>>>(
        h2f, KFC, Wt, KFC, KPERSLICE / BK, KPERSLICE, part, HDIM, nullptr, nullptr);

    reduceFc1<<<(BATCH * HDIM + 255) / 256, 256, 0, stream>>>(part, bf1, h3);

    fc2_softmax<<<BATCH / 4, 256, 0, stream>>>(h3, wf2, bf2, out);
}

// Round 2
// 306.261 us; speedup vs baseline: 1.1608x; 1.1608x over previous
//
#include <hip/hip_runtime.h>
#include <hip/hip_bf16.h>
#include <math.h>

// Problem constants
#define BATCH 1024
#define NREAL 784
#define NPAD  896      // 7*128, zero-padded graph dim
#define C1D   32
#define C2D   32
#define HDIM  512
#define NCLS  10
#define KFC   25088    // 784*32

#define KS_G1 4        // split-K for G1 (K=896 -> 224/slice, 7 iters)
#define KS_FC 16       // split-K for fc1 (K=25088 -> 1568/slice, 49 iters)

// GEMM tile
#define BM 128
#define BN 128
#define BK 32

using bf16x8  = __attribute__((ext_vector_type(8))) __bf16;
using floatx4 = __attribute__((ext_vector_type(4))) float;

__device__ __forceinline__ void gll16(const void* g, void* l) {
    // async global->LDS, 16B per lane; LDS dest is wave-uniform base + lane*16
    __builtin_amdgcn_global_load_lds((const __attribute__((address_space(1))) void*)g,
                                     (__attribute__((address_space(3))) void*)l,
                                     16, 0, 0);
}

__device__ __forceinline__ float elu_f(float t) {
    return t > 0.f ? t : (__expf(t) - 1.f);
}

// ---------------------------------------------------------------------------
// BT-GEMM, double-buffered LDS (1 barrier per k-iter; loads for iter k+1 are
// in flight during compute of iter k — the barrier's vmcnt(0) drain then waits
// on loads that already had a full compute phase to progress).
// C[row][col] = sum_k A[row][k] * Bm[col][k]   (both k-contiguous)
// 128x128 tile, 256 thr (4 waves, 2x2 of 64x64), BK=32, mfma 16x16x32 bf16.
// MODE 1: elu(acc+bias[col&31]) -> bf16 outH[(col>>5)*KFC+row*32+(col&31)],
//         masked to row<784                                           (G3)
// MODE 2: fp32 partial store outF[z*sliceStride + row*ldc + col]   (G1, G4)
// ---------------------------------------------------------------------------
template<int MODE>
__launch_bounds__(256)
__global__ void gemm_bt(const __hip_bfloat16* __restrict__ A, int lda,
                        const __hip_bfloat16* __restrict__ Bm, int ldb,
                        int kIters, int kPerZ, size_t sliceStride,
                        float* __restrict__ outF, int ldc,
                        __hip_bfloat16* __restrict__ outH,
                        const float* __restrict__ bias)
{
    __shared__ __align__(16) __hip_bfloat16 As[2][BM * BK];
    __shared__ __align__(16) __hip_bfloat16 Bs[2][BN * BK];

    const int tid  = threadIdx.x;
    const int lane = tid & 63;
    const int wave = tid >> 6;
    const int wi = wave >> 1, wj = wave & 1;

    const int m0 = blockIdx.y * BM;
    const int n0 = blockIdx.x * BN;
    const int kBase = blockIdx.z * kPerZ;

    const int rowInChunk = lane >> 2;       // 16 rows per 1KB chunk
    const int kOff8 = (lane & 3) * 8;       // 4 lanes cover 32 bf16 per row

    // per-thread global source pointers (advance by BK each stage)
    const __hip_bfloat16* aSrc[2];
    const __hip_bfloat16* bSrc[2];
    #pragma unroll
    for (int c = 0; c < 2; c++) {
        const int r = (wave * 2 + c) * 16 + rowInChunk;
        aSrc[c] = A  + (size_t)(m0 + r) * lda + kBase + kOff8;
        bSrc[c] = Bm + (size_t)(n0 + r) * ldb + kBase + kOff8;
    }

    floatx4 acc[4][4];
    const floatx4 zero4 = {0.f, 0.f, 0.f, 0.f};
    #pragma unroll
    for (int i = 0; i < 4; i++)
        #pragma unroll
        for (int j = 0; j < 4; j++) acc[i][j] = zero4;

    // prologue: stage iter 0 into buffer 0
    #pragma unroll
    for (int c = 0; c < 2; c++) {
        const int chunk = wave * 2 + c;
        gll16(aSrc[c], &As[0][chunk * 512]);
        gll16(bSrc[c], &Bs[0][chunk * 512]);
        aSrc[c] += BK; bSrc[c] += BK;
    }

    for (int kt = 0; kt < kIters; ++kt) {
        const int buf = kt & 1;
        __syncthreads();   // drains vmcnt(0): buffer `buf` is now populated

        if (kt + 1 < kIters) {
            const int nbuf = buf ^ 1;
            #pragma unroll
            for (int c = 0; c < 2; c++) {
                const int chunk = wave * 2 + c;
                gll16(aSrc[c], &As[nbuf][chunk * 512]);
                gll16(bSrc[c], &Bs[nbuf][chunk * 512]);
                aSrc[c] += BK; bSrc[c] += BK;
            }
        }

        bf16x8 af[4], bfr[4];
        #pragma unroll
        for (int mi = 0; mi < 4; mi++)
            af[mi] = *(const bf16x8*)(&As[buf][(wi * 64 + mi * 16 + (lane & 15)) * BK + (lane >> 4) * 8]);
        #pragma unroll
        for (int nj = 0; nj < 4; nj++)
            bfr[nj] = *(const bf16x8*)(&Bs[buf][(wj * 64 + nj * 16 + (lane & 15)) * BK + (lane >> 4) * 8]);

        #pragma unroll
        for (int mi = 0; mi < 4; mi++)
            #pragma unroll
            for (int nj = 0; nj < 4; nj++)
                acc[mi][nj] = __builtin_amdgcn_mfma_f32_16x16x32_bf16(af[mi], bfr[nj], acc[mi][nj], 0, 0, 0);
        // NOTE: no trailing barrier — next iteration's barrier protects buf reuse:
        // staging into `nbuf` only happens after ALL waves passed the barrier that
        // followed their compute-from-`nbuf` (two iterations ago).
    }

    // epilogue: C/D layout col=lane&15, row=(lane>>4)*4+reg  [verified m89/m91]
    #pragma unroll
    for (int mi = 0; mi < 4; mi++) {
        #pragma unroll
        for (int nj = 0; nj < 4; nj++) {
            #pragma unroll
            for (int r = 0; r < 4; r++) {
                const int row = m0 + wi * 64 + mi * 16 + (lane >> 4) * 4 + r;
                const int col = n0 + wj * 64 + nj * 16 + (lane & 15);
                const float v = acc[mi][nj][r];
                if (MODE == 1) {
                    if (row < NREAL) {
                        const int c = col & 31, b = col >> 5;
                        const float t = elu_f(v + bias[c]);
                        outH[(size_t)b * KFC + row * 32 + c] = __float2bfloat16(t);
                    }
                } else {
                    outF[(size_t)blockIdx.z * sliceStride + (size_t)row * ldc + col] = v;
                }
            }
        }
    }
}

// ---------------------------------------------------------------------------
// Conversions / padding
// ---------------------------------------------------------------------------
__global__ void convX(const float* __restrict__ x, __hip_bfloat16* __restrict__ Xbf) {
    const int idx = blockIdx.x * 256 + threadIdx.x;
    if (idx >= BATCH * NPAD) return;
    const int m = idx % NPAD, b = idx / NPAD;
    const float v = (m < NREAL) ? x[(size_t)b * NREAL + m] : 0.f;
    Xbf[idx] = __float2bfloat16(v);
}

__global__ void convA(const float* __restrict__ a, __hip_bfloat16* __restrict__ Abf) {
    const int idx = blockIdx.x * 256 + threadIdx.x;
    if (idx >= NPAD * NPAD) return;
    const int m = idx % NPAD, n = idx / NPAD;
    const float v = (m < NREAL && n < NREAL) ? a[(size_t)n * NREAL + m] : 0.f;
    Abf[idx] = __float2bfloat16(v);
}

// wf1 [25088][512] fp32 -> Wt [512][25088] bf16 (LDS tile transpose)
__global__ void convW(const float* __restrict__ wf1, __hip_bfloat16* __restrict__ Wt) {
    __shared__ float tile[32][33];
    const int k0 = blockIdx.x * 32, h0 = blockIdx.y * 32;
    const int tx = threadIdx.x, ty = threadIdx.y;  // (32,8)
    #pragma unroll
    for (int i = 0; i < 4; i++)
        tile[ty * 4 + i][tx] = wf1[(size_t)(k0 + ty * 4 + i) * HDIM + h0 + tx];
    __syncthreads();
    #pragma unroll
    for (int i = 0; i < 4; i++)
        Wt[(size_t)(h0 + ty * 4 + i) * KFC + k0 + tx] = __float2bfloat16(tile[tx][ty * 4 + i]);
}

// ---------------------------------------------------------------------------
// Layer-1 fused pointwise: reduce 4 Y split-K partials, then
// T_t[(b*32+c)][m] = sum_c' elu(Y[b][m]*w1[c']+b1[c'])*W2[c'][c]
// ---------------------------------------------------------------------------
__global__ void layer1_fuse(const float* __restrict__ Ypart,
                            const float* __restrict__ w1, const float* __restrict__ b1,
                            const float* __restrict__ w2,
                            __hip_bfloat16* __restrict__ Tt)
{
    __shared__ __align__(16) float sW2[C1D * C2D];
    __shared__ float sw1[C1D], sb1[C1D];
    const int tid = threadIdx.x;                 // 128 threads
    for (int i = tid; i < C1D * C2D; i += 128) sW2[i] = w2[i];
    if (tid < C1D) { sw1[tid] = w1[tid]; sb1[tid] = b1[tid]; }
    __syncthreads();

    const int m = blockIdx.x * 128 + tid;        // 0..895
    const int b = blockIdx.y;
    float y = 0.f;
    #pragma unroll
    for (int z = 0; z < KS_G1; z++)
        y += Ypart[(size_t)z * (BATCH * NPAD) + (size_t)b * NPAD + m];

    float h[C1D];
    #pragma unroll
    for (int c1 = 0; c1 < C1D; c1++) h[c1] = elu_f(y * sw1[c1] + sb1[c1]);

    float4 t4[8];
    #pragma unroll
    for (int q = 0; q < 8; q++) t4[q] = make_float4(0.f, 0.f, 0.f, 0.f);
    #pragma unroll
    for (int c1 = 0; c1 < C1D; c1++) {
        const float hv = h[c1];
        const float4* row = (const float4*)(sW2 + c1 * C2D);
        #pragma unroll
        for (int q = 0; q < 8; q++) {
            const float4 w = row[q];
            t4[q].x += hv * w.x; t4[q].y += hv * w.y;
            t4[q].z += hv * w.z; t4[q].w += hv * w.w;
        }
    }
    const float* tf = (const float*)t4;
    #pragma unroll
    for (int c = 0; c < C2D; c++)
        Tt[((size_t)(b * 32 + c)) * NPAD + m] = __float2bfloat16(tf[c]);
}

// ---------------------------------------------------------------------------
// fc1 split-K reduce: h3[b][h] = relu(bf1[h] + sum_z part[z][b][h])
// ---------------------------------------------------------------------------
__global__ void reduceFc1(const float* __restrict__ part, const float* __restrict__ bf1,
                          float* __restrict__ h3)
{
    const int idx = blockIdx.x * 256 + threadIdx.x;
    if (idx >= BATCH * HDIM) return;
    float s = 0.f;
    #pragma unroll
    for (int z = 0; z < KS_FC; z++) s += part[(size_t)z * (BATCH * HDIM) + idx];
    s += bf1[idx & (HDIM - 1)];
    h3[idx] = s > 0.f ? s : 0.f;
}

// ---------------------------------------------------------------------------
// fc2 + softmax: one wave per batch row
// ---------------------------------------------------------------------------
__global__ void fc2_softmax(const float* __restrict__ h3, const float* __restrict__ wf2,
                            const float* __restrict__ bf2, float* __restrict__ out)
{
    __shared__ float sW[HDIM * NCLS];
    __shared__ float sb[NCLS];
    const int tid = threadIdx.x;                 // 256
    for (int i = tid; i < HDIM * NCLS; i += 256) sW[i] = wf2[i];
    if (tid < NCLS) sb[tid] = bf2[tid];
    __syncthreads();

    const int lane = tid & 63, wave = tid >> 6;
    const int b = blockIdx.x * 4 + wave;

    float acc[NCLS];
    #pragma unroll
    for (int c = 0; c < NCLS; c++) acc[c] = 0.f;
    #pragma unroll
    for (int q = 0; q < 8; q++) {
        const int h = q * 64 + lane;
        const float hv = h3[(size_t)b * HDIM + h];
        #pragma unroll
        for (int c = 0; c < NCLS; c++) acc[c] += hv * sW[h * NCLS + c];
    }
    #pragma unroll
    for (int c = 0; c < NCLS; c++) {
        #pragma unroll
        for (int off = 32; off >= 1; off >>= 1) acc[c] += __shfl_down(acc[c], off);
    }
    if (lane == 0) {
        float mx = -1e30f;
        #pragma unroll
        for (int c = 0; c < NCLS; c++) { acc[c] += sb[c]; mx = fmaxf(mx, acc[c]); }
        float e[NCLS], s = 0.f;
        #pragma unroll
        for (int c = 0; c < NCLS; c++) { e[c] = __expf(acc[c] - mx); s += e[c]; }
        const float inv = 1.f / s;
        #pragma unroll
        for (int c = 0; c < NCLS; c++) out[(size_t)b * NCLS + c] = e[c] * inv;
    }
}

// ---------------------------------------------------------------------------
// Workspace layout (peak 115.6 MB; proven ws >= 121.4 MB from round 1)
//   h2f   [0,          51380224)  bf16 1024x25088  (written G3, read G4)
//     Ypart [0, 14680064) f32 4x1024x896 — overlay, dead before G3 writes h2f
//   Tt    [51380224,  110100480)  bf16 32768x896   (dead after G3)
//     Wt   [51380224, 77070336)   bf16 512x25088 — overlay after G3
//     part [77070336, 110624768)  f32 16x1024x512 — overlay after G3
//            (spills 0.5 MB into Abf region; Abf dead after G3)
//   Abf   [110100480, 111706112)  bf16 896x896     (dead after G3)
//   Xbf   [111706112, 113541120)  bf16 1024x896    (dead after G1)
//   h3    [113541120, 115638272)  f32 1024x512
// ---------------------------------------------------------------------------
extern "C" void kernel_launch(void* const* d_in, const int* in_sizes, int n_in,
                              void* d_out, int out_size, void* d_ws, size_t ws_size,
                              hipStream_t stream)
{
    const float* x   = (const float*)d_in[0];
    const float* a   = (const float*)d_in[1];
    const float* w1  = (const float*)d_in[2];
    const float* b1  = (const float*)d_in[3];
    const float* w2  = (const float*)d_in[4];
    const float* b2  = (const float*)d_in[5];
    const float* wf1 = (const float*)d_in[6];
    const float* bf1 = (const float*)d_in[7];
    const float* wf2 = (const float*)d_in[8];
    const float* bf2 = (const float*)d_in[9];
    float* out = (float*)d_out;

    char* ws = (char*)d_ws;
    __hip_bfloat16* h2f  = (__hip_bfloat16*)(ws + 0);
    float*          Ypart= (float*)(ws + 0);                  // overlay (pre-G3)
    __hip_bfloat16* Tt   = (__hip_bfloat16*)(ws + 51380224);
    __hip_bfloat16* Wt   = (__hip_bfloat16*)(ws + 51380224);  // overlay (post-G3)
    float*          part = (float*)(ws + 77070336);           // overlay (post-G3)
    __hip_bfloat16* Abf  = (__hip_bfloat16*)(ws + 110100480);
    __hip_bfloat16* Xbf  = (__hip_bfloat16*)(ws + 111706112);
    float*          h3   = (float*)(ws + 113541120);

    convX<<<(BATCH * NPAD + 255) / 256, 256, 0, stream>>>(x, Xbf);
    convA<<<(NPAD * NPAD + 255) / 256, 256, 0, stream>>>(a, Abf);

    // G1: Ypart[z][b][n] partials of sum_m Xbf[b][m]*Abf[n][m]
    //     (M=1024, N=896, K=224/slice, split-K=4 -> 224 blocks)
    gemm_bt<2><<<dim3(NPAD / BN, BATCH / BM, KS_G1), 256, 0, stream>>>(
        Xbf, NPAD, Abf, NPAD, (NPAD / KS_G1) / BK, NPAD / KS_G1,
        (size_t)BATCH * NPAD, Ypart, NPAD, nullptr, nullptr);

    // layer-1 pointwise + @W2, transposed store (reduces Ypart internally)
    layer1_fuse<<<dim3(NPAD / 128, BATCH), 128, 0, stream>>>(Ypart, w1, b1, w2, Tt);

    // G3: h2 = elu(A @ T + b2);  C[n][(b,c)] (M=896, N=32768, K=896 -> 1792 blocks)
    gemm_bt<1><<<dim3((BATCH * 32) / BN, NPAD / BM, 1), 256, 0, stream>>>(
        Abf, NPAD, Tt, NPAD, NPAD / BK, 0, 0, nullptr, 0, h2f, b2);

    // transpose wf1 -> bf16 (into the now-dead Tt region)
    convW<<<dim3(KFC / 32, HDIM / 32), dim3(32, 8), 0, stream>>>(wf1, Wt);

    // G4: fc1 partials, split-K=16 (M=1024, N=512, K=1568/slice -> 512 blocks)
    gemm_bt<2><<<dim3(HDIM / BN, BATCH / BM, KS_FC), 256, 0, stream>>>(
        h2f, KFC, Wt, KFC, (KFC / KS_FC) / BK, KFC / KS_FC,
        (size_t)BATCH * HDIM, part, HDIM, nullptr, nullptr);

    reduceFc1<<<(BATCH * HDIM + 255) / 256, 256, 0, stream>>>(part, bf1, h3);

    fc2_softmax<<<BATCH / 4, 256, 0, stream>>>(h3, wf2, bf2, out);
}